// Round 6
// baseline (808.798 us; speedup 1.0000x reference)
//
#include <hip/hip_runtime.h>
#include <cstdint>
#include <cstddef>

#define NN 100000
#define RR 3
#define EE 500000
#define RN 300000   // RR*NN
#define RE 1500000  // RR*EE
#define CAP 32      // padded-CSR slots per (rel,node)

typedef unsigned short u16;
typedef unsigned int   u32;
typedef __attribute__((ext_vector_type(8))) short bhalf8;
typedef __attribute__((ext_vector_type(4))) float f32x4;

static inline int cdiv_h(int a, int b){ return (a+b-1)/b; }

__device__ __forceinline__ float bf_lo(u32 v){ union{u32 u; float f;} c; c.u = v<<16; return c.f; }
__device__ __forceinline__ float bf_hi(u32 v){ union{u32 u; float f;} c; c.u = v & 0xffff0000u; return c.f; }
__device__ __forceinline__ u16 f2bf(float f){
  union{float f; u32 u;} c; c.f = f;
  u32 r = (c.u + 0x7FFFu + ((c.u >> 16) & 1u)) >> 16;  // RNE
  return (u16)r;
}
__device__ __forceinline__ u32 pk2(float a, float b){ return (u32)f2bf(a) | ((u32)f2bf(b)<<16); }

// ---------------- init: cursors + dout counters ----------------
__global__ __launch_bounds__(256) void k_init(int* __restrict__ cursor, int* __restrict__ dout_cnt){
  int i = blockIdx.x*256 + threadIdx.x;
  if (i < RN){ cursor[i] = i*CAP; dout_cnt[i] = 0; }
}

// ---------------- fused: CSR fill+dout hist (atomic) || x->bf16 || W transposes ----------------
// blocks [0,5860) edges  [5860,12110) cvt_x  [12110,12686) Wt012  [12686,12734) Wt3
__global__ __launch_bounds__(256) void k_pre1f(const int* __restrict__ src, const int* __restrict__ dst,
    int* __restrict__ cursor, int* __restrict__ dout_cnt, int* __restrict__ edge_src,
    const float* __restrict__ x, u16* __restrict__ xb,
    const float* __restrict__ W0, const float* __restrict__ W1, const float* __restrict__ W2,
    const float* __restrict__ W3, u16* __restrict__ Wtb, u16* __restrict__ Wt3b){
  int b = blockIdx.x, t = threadIdx.x;
  if (b < 5860){
    int i = b*256 + t;
    if (i < RE){
      int r = i / EE;
      int s = src[i], d = dst[i];
      atomicAdd(&dout_cnt[r*NN + s], 1);
      int idx = r*NN + d;
      int pos = atomicAdd(&cursor[idx], 1);
      if (pos < idx*CAP + CAP) edge_src[pos] = s;   // overflow guard (P ~ 0)
    }
  } else if (b < 12110){
    int i = (b-5860)*256 + t;                       // 8 f32 -> 8 bf16
    if (i < NN*128/8){
      float4 v0 = ((const float4*)x)[i*2];
      float4 v1 = ((const float4*)x)[i*2+1];
      uint4 o;
      o.x = pk2(v0.x, v0.y); o.y = pk2(v0.z, v0.w);
      o.z = pk2(v1.x, v1.y); o.w = pk2(v1.z, v1.w);
      ((uint4*)xb)[i] = o;
    }
  } else if (b < 12686){
    int gid = (b-12110)*256 + t;                    // 3 layers x [3][128][128]
    if (gid < 3*3*16384){
      int l = gid / 49152; int rem = gid - l*49152; // rem = (r*128+k)*128+n
      int r = rem >> 14; int rem2 = rem & 16383;
      int k = rem2 >> 7; int n = rem2 & 127;
      const float* Wl = (l==0) ? W0 : (l==1) ? W1 : W2;
      Wtb[((size_t)(l*3+r))*16384 + (size_t)n*128 + k] = f2bf(Wl[rem]);
    }
  } else {
    int gid = (b-12686)*256 + t;                    // [3][128][32]
    if (gid < 3*4096){
      int r = gid >> 12; int rem = gid & 4095;
      int k = rem >> 5; int n = rem & 31;
      Wt3b[(size_t)(r*32+n)*128 + k] = f2bf(W3[gid]);
    }
  }
}

__global__ __launch_bounds__(256) void k_norms(const int* __restrict__ dout_cnt, float* __restrict__ dout_is){
  int i = blockIdx.x*256 + threadIdx.x;
  if (i < RN){
    int dc = dout_cnt[i] > 1 ? dout_cnt[i] : 1;
    dout_is[i] = rsqrtf((float)dc);
  }
}

// ---------------- fused layer: gather-aggregate into LDS + MFMA GEMM + per-rel ReLU ----------------
// block = 128 output rows; 4 waves. Agg: 16-lane group per node (4 nodes/wave concurrent),
// lane k covers feats 8k..8k+7; 2-edge unrolled independent gathers. A-tile never touches global.
__global__ __launch_bounds__(256) void k_layer(const u16* __restrict__ h, const u16* __restrict__ Wt,
    const float* __restrict__ bias, const int* __restrict__ cursor,
    const int* __restrict__ edge_src, const float* __restrict__ dout_is, u16* __restrict__ out){
  __shared__ __align__(16) u16 As[128*128];
  __shared__ __align__(16) u16 Bs[128*128];
  int t = threadIdx.x;
  int l = t & 63, w = t >> 6;
  int wr = w >> 1, wc = w & 1;
  int row0 = blockIdx.x * 128;
  int tr = t >> 4, tc = t & 15;       // B staging coords
  int g = l >> 4, k = l & 15;         // agg: group, feat chunk

  const uint4* __restrict__ h4 = (const uint4*)h;

  f32x4 res[4][4];
  #pragma unroll
  for (int m=0;m<4;m++)
    #pragma unroll
    for (int n=0;n<4;n++) res[m][n] = (f32x4){0.f,0.f,0.f,0.f};

  for (int r=0; r<RR; r++){
    if (r > 0) __syncthreads();       // prev MFMA done reading As/Bs

    // issue B-tile loads early; they complete during the gather phase
    uint4 rb[8];
    #pragma unroll
    for (int it=0; it<8; ++it)
      rb[it] = *(const uint4*)&Wt[(size_t)r*16384 + (size_t)(it*16+tr)*128 + tc*8];

    const float* __restrict__ dis = dout_is + r*NN;

    // aggregate 8 quads of 4 nodes -> swizzled As
    #pragma unroll 2
    for (int qd=0; qd<8; ++qd){
      int nl = w*32 + qd*4 + g;
      int node = row0 + nl;
      float a[8] = {0.f,0.f,0.f,0.f,0.f,0.f,0.f,0.f};
      int cnt = 0;
      if (node < NN){
        int widx = r*NN + node;
        int base = widx*CAP;
        cnt = cursor[widx] - base;
        if (cnt > CAP) cnt = CAP;
        int e = 0;
        for (; e+2 <= cnt; e += 2){
          int sa = edge_src[base+e], sb = edge_src[base+e+1];
          float wa = dis[sa], wb = dis[sb];
          uint4 va = h4[(size_t)sa*16 + k];
          uint4 vb = h4[(size_t)sb*16 + k];
          a[0]+=wa*bf_lo(va.x); a[1]+=wa*bf_hi(va.x); a[2]+=wa*bf_lo(va.y); a[3]+=wa*bf_hi(va.y);
          a[4]+=wa*bf_lo(va.z); a[5]+=wa*bf_hi(va.z); a[6]+=wa*bf_lo(va.w); a[7]+=wa*bf_hi(va.w);
          a[0]+=wb*bf_lo(vb.x); a[1]+=wb*bf_hi(vb.x); a[2]+=wb*bf_lo(vb.y); a[3]+=wb*bf_hi(vb.y);
          a[4]+=wb*bf_lo(vb.z); a[5]+=wb*bf_hi(vb.z); a[6]+=wb*bf_lo(vb.w); a[7]+=wb*bf_hi(vb.w);
        }
        if (e < cnt){
          int s = edge_src[base+e];
          float wa = dis[s];
          uint4 v = h4[(size_t)s*16 + k];
          a[0]+=wa*bf_lo(v.x); a[1]+=wa*bf_hi(v.x); a[2]+=wa*bf_lo(v.y); a[3]+=wa*bf_hi(v.y);
          a[4]+=wa*bf_lo(v.z); a[5]+=wa*bf_hi(v.z); a[6]+=wa*bf_lo(v.w); a[7]+=wa*bf_hi(v.w);
        }
      }
      float di = rsqrtf((float)(cnt > 1 ? cnt : 1));
      uint4 o;
      o.x = pk2(a[0]*di, a[1]*di); o.y = pk2(a[2]*di, a[3]*di);
      o.z = pk2(a[4]*di, a[5]*di); o.w = pk2(a[6]*di, a[7]*di);
      *(uint4*)&As[nl*128 + ((k ^ (nl&7))*8)] = o;
    }

    // write B-tile (swizzled)
    #pragma unroll
    for (int it=0; it<8; ++it){
      int rho = it*16 + tr;
      *(uint4*)&Bs[rho*128 + ((tc ^ (tr&7))*8)] = rb[it];
    }
    __syncthreads();

    // MFMA: 64x64 per wave, K=128
    f32x4 acc[4][4];
    #pragma unroll
    for (int m=0;m<4;m++)
      #pragma unroll
      for (int n=0;n<4;n++) acc[m][n] = (f32x4){0.f,0.f,0.f,0.f};

    #pragma unroll
    for (int kk=0; kk<4; ++kk){
      bhalf8 af[4], bf[4];
      #pragma unroll
      for (int m=0;m<4;m++){
        int rho = wr*64 + m*16 + (l&15);
        int ch = (kk*4 + (l>>4)) ^ (l&7);
        af[m] = *(const bhalf8*)&As[rho*128 + ch*8];
      }
      #pragma unroll
      for (int n=0;n<4;n++){
        int rho = wc*64 + n*16 + (l&15);
        int ch = (kk*4 + (l>>4)) ^ (l&7);
        bf[n] = *(const bhalf8*)&Bs[rho*128 + ch*8];
      }
      #pragma unroll
      for (int m=0;m<4;m++)
        #pragma unroll
        for (int n=0;n<4;n++)
          acc[m][n] = __builtin_amdgcn_mfma_f32_16x16x32_bf16(af[m], bf[n], acc[m][n], 0, 0, 0);
    }

    // bias + relu, accumulate across relations
    #pragma unroll
    for (int n=0;n<4;n++){
      int col = wc*64 + n*16 + (l&15);
      float bb = bias[r*128 + col];
      #pragma unroll
      for (int m=0;m<4;m++)
        #pragma unroll
        for (int i=0;i<4;i++){
          float v = acc[m][n][i] + bb;
          res[m][n][i] += v > 0.f ? v : 0.f;
        }
    }
  }

  // store bf16 h_out
  #pragma unroll
  for (int m=0;m<4;m++)
    #pragma unroll
    for (int i=0;i<4;i++){
      int grow = row0 + wr*64 + m*16 + (l>>4)*4 + i;
      if (grow < NN){
        #pragma unroll
        for (int n=0;n<4;n++)
          out[(size_t)grow*128 + wc*64 + n*16 + (l&15)] = f2bf(res[m][n][i]);
      }
    }
}

// ---------------- layer-3 transform GEMM: y[n][r*32+j] ----------------
__global__ __launch_bounds__(256) void k_mm_y(const u16* __restrict__ A, const u16* __restrict__ Wt3,
    u16* __restrict__ y){
  __shared__ __align__(16) u16 As[128*128];
  __shared__ __align__(16) u16 Bs[96*128];
  int t = threadIdx.x;
  int l = t & 63, w = t >> 6;
  int wr = w & 1, wc = w >> 1;
  int row0 = blockIdx.x * 128;
  int tr = t >> 4, tc = t & 15;
  int swz = tr & 7;

  uint4 ra[8], rb[6];
  #pragma unroll
  for (int it=0; it<8; ++it){
    int grow = row0 + it*16 + tr;
    if (grow > NN-1) grow = NN-1;
    ra[it] = *(const uint4*)&A[(size_t)grow*128 + tc*8];
  }
  #pragma unroll
  for (int it=0; it<6; ++it)
    rb[it] = *(const uint4*)&Wt3[(size_t)(it*16 + tr)*128 + tc*8];
  #pragma unroll
  for (int it=0; it<8; ++it)
    *(uint4*)&As[(it*16+tr)*128 + ((tc ^ swz)*8)] = ra[it];
  #pragma unroll
  for (int it=0; it<6; ++it)
    *(uint4*)&Bs[(it*16+tr)*128 + ((tc ^ swz)*8)] = rb[it];
  __syncthreads();

  f32x4 acc[4][3];
  #pragma unroll
  for (int m=0;m<4;m++)
    #pragma unroll
    for (int n=0;n<3;n++) acc[m][n] = (f32x4){0.f,0.f,0.f,0.f};

  #pragma unroll
  for (int kk=0; kk<4; ++kk){
    bhalf8 af[4], bf[3];
    #pragma unroll
    for (int m=0;m<4;m++){
      int rho = wr*64 + m*16 + (l&15);
      int ch = (kk*4 + (l>>4)) ^ (l&7);
      af[m] = *(const bhalf8*)&As[rho*128 + ch*8];
    }
    #pragma unroll
    for (int n=0;n<3;n++){
      int rho = wc*48 + n*16 + (l&15);
      int ch = (kk*4 + (l>>4)) ^ (l&7);
      bf[n] = *(const bhalf8*)&Bs[rho*128 + ch*8];
    }
    #pragma unroll
    for (int m=0;m<4;m++)
      #pragma unroll
      for (int n=0;n<3;n++)
        acc[m][n] = __builtin_amdgcn_mfma_f32_16x16x32_bf16(af[m], bf[n], acc[m][n], 0, 0, 0);
  }

  #pragma unroll
  for (int m=0;m<4;m++)
    #pragma unroll
    for (int i=0;i<4;i++){
      int grow = row0 + wr*64 + m*16 + (l>>4)*4 + i;
      if (grow < NN){
        #pragma unroll
        for (int n=0;n<3;n++)
          y[(size_t)grow*96 + wc*48 + n*16 + (l&15)] = f2bf(acc[m][n][i]);
      }
    }
}

// ---------------- final aggregation over 32 feats: 8 lane-groups x 4 feats ----------------
__global__ __launch_bounds__(256) void k_agg_out(const u16* __restrict__ y, float* __restrict__ out,
    const int* __restrict__ cursor, const int* __restrict__ edge_src,
    const float* __restrict__ dout_is, const float* __restrict__ b3){
  int n = (blockIdx.x*256 + threadIdx.x) >> 6;
  if (n >= NN) return;
  int l = threadIdx.x & 63;
  int g = l >> 3, k = l & 7;
  float res[4];
  #pragma unroll
  for (int i=0;i<4;i++) res[i] = b3[4*k+i] + b3[32+4*k+i] + b3[64+4*k+i];
  const uint2* __restrict__ y2 = (const uint2*)y;   // y row = 24 uint2
  for (int r=0; r<RR; r++){
    int w = r*NN + n;
    int s0 = w*CAP;
    int s1 = cursor[w];
    if (s1 > s0 + CAP) s1 = s0 + CAP;
    const float* __restrict__ dis = dout_is + r*NN;
    float a[4] = {0.f,0.f,0.f,0.f};
    for (int p = s0 + g; p < s1; p += 8){
      int s = edge_src[p];
      float wg = dis[s];
      uint2 v = y2[(size_t)s*24 + r*8 + k];
      a[0] += wg*bf_lo(v.x); a[1] += wg*bf_hi(v.x);
      a[2] += wg*bf_lo(v.y); a[3] += wg*bf_hi(v.y);
    }
    #pragma unroll
    for (int i=0;i<4;i++){
      a[i] += __shfl_xor(a[i], 8);
      a[i] += __shfl_xor(a[i], 16);
      a[i] += __shfl_xor(a[i], 32);
    }
    int cnt = s1 - s0;
    float di = rsqrtf((float)(cnt>1?cnt:1));
    #pragma unroll
    for (int i=0;i<4;i++) res[i] += di*a[i];
  }
  if (g == 0)
    ((float4*)out)[(size_t)n*8 + k] = make_float4(res[0],res[1],res[2],res[3]);
}

// ---------------- launch ----------------

extern "C" void kernel_launch(void* const* d_in, const int* in_sizes, int n_in,
                              void* d_out, int out_size, void* d_ws, size_t ws_size,
                              hipStream_t stream){
  const float* x   = (const float*)d_in[0];
  const int*   src = (const int*)d_in[1];
  const int*   dst = (const int*)d_in[2];
  const float* W0  = (const float*)d_in[3]; const float* b0 = (const float*)d_in[4];
  const float* W1  = (const float*)d_in[5]; const float* b1 = (const float*)d_in[6];
  const float* W2  = (const float*)d_in[7]; const float* b2 = (const float*)d_in[8];
  const float* W3  = (const float*)d_in[9]; const float* b3 = (const float*)d_in[10];
  float* out = (float*)d_out;

  // workspace layout (~113 MB; known-good ws >= ~141 MB)
  char* p = (char*)d_ws;
  auto alloc = [&](size_t bytes)->char*{
    char* q = p; p += (bytes + 255) & ~(size_t)255; return q;
  };
  int*   cursor   = (int*)  alloc(RN*4);
  int*   dout_cnt = (int*)  alloc(RN*4);
  float* dout_is  = (float*)alloc(RN*4);
  u16*   Wtb      = (u16*)  alloc((size_t)3*3*16384*2);
  u16*   Wt3b     = (u16*)  alloc((size_t)3*32*128*2);
  u16*   y        = (u16*)  alloc((size_t)NN*96*2);    // 19.2 MB
  u16*   bufA     = (u16*)  alloc((size_t)NN*128*2);   // 25.6 MB
  u16*   bufB     = (u16*)  alloc((size_t)NN*128*2);   // 25.6 MB (xb first)
  int*   edge_src = (int*)  alloc((size_t)RN*CAP*4);   // 38.4 MB padded CSR

  k_init <<<cdiv_h(RN,256),256,0,stream>>>(cursor, dout_cnt);
  k_pre1f<<<12734,256,0,stream>>>(src, dst, cursor, dout_cnt, edge_src,
                                  x, bufB, W0,W1,W2,W3, Wtb, Wt3b);
  k_norms<<<cdiv_h(RN,256),256,0,stream>>>(dout_cnt, dout_is);

  int mm_blocks = cdiv_h(NN,128);
  // layers 0..2: fused gather-agg + GEMM + ReLU
  k_layer<<<mm_blocks,256,0,stream>>>(bufB, Wtb,           b0, cursor, edge_src, dout_is, bufA);
  k_layer<<<mm_blocks,256,0,stream>>>(bufA, Wtb + 3*16384, b1, cursor, edge_src, dout_is, bufB);
  k_layer<<<mm_blocks,256,0,stream>>>(bufB, Wtb + 6*16384, b2, cursor, edge_src, dout_is, bufA);
  // layer 3: transform-first then 32-feat aggregation
  k_mm_y<<<mm_blocks,256,0,stream>>>(bufA, Wt3b, y);
  k_agg_out<<<cdiv_h(NN,4),256,0,stream>>>(y, out, cursor, edge_src, dout_is, b3);
}

// Round 7
// 776.263 us; speedup vs baseline: 1.0419x; 1.0419x over previous
//
#include <hip/hip_runtime.h>
#include <cstdint>
#include <cstddef>

#define NN 100000
#define RR 3
#define EE 500000
#define RN 300000   // RR*NN
#define RE 1500000  // RR*EE
#define KK 384      // RR*128
#define CAP 32      // padded-CSR slots per (rel,node)

typedef unsigned short u16;
typedef unsigned int   u32;
typedef __attribute__((ext_vector_type(8))) short bhalf8;
typedef __attribute__((ext_vector_type(4))) float f32x4;

static inline int cdiv_h(int a, int b){ return (a+b-1)/b; }

__device__ __forceinline__ float bf_lo(u32 v){ union{u32 u; float f;} c; c.u = v<<16; return c.f; }
__device__ __forceinline__ float bf_hi(u32 v){ union{u32 u; float f;} c; c.u = v & 0xffff0000u; return c.f; }
__device__ __forceinline__ u16 f2bf(float f){
  union{float f; u32 u;} c; c.f = f;
  u32 r = (c.u + 0x7FFFu + ((c.u >> 16) & 1u)) >> 16;  // RNE
  return (u16)r;
}
__device__ __forceinline__ u32 pk2(float a, float b){ return (u32)f2bf(a) | ((u32)f2bf(b)<<16); }

// ---------------- init: cursors + dout counters ----------------
__global__ __launch_bounds__(256) void k_init(int* __restrict__ cursor, int* __restrict__ dout_cnt){
  int i = blockIdx.x*256 + threadIdx.x;
  if (i < RN){ cursor[i] = i*CAP; dout_cnt[i] = 0; }
}

// ---------------- fused: CSR fill+dout hist (atomic) || x->bf16 || W transposes ----------------
// blocks [0,5860) edges  [5860,12110) cvt_x  [12110,12686) Wt012  [12686,12734) Wt3
__global__ __launch_bounds__(256) void k_pre1f(const int* __restrict__ src, const int* __restrict__ dst,
    int* __restrict__ cursor, int* __restrict__ dout_cnt, int* __restrict__ edge_src,
    const float* __restrict__ x, u16* __restrict__ xb,
    const float* __restrict__ W0, const float* __restrict__ W1, const float* __restrict__ W2,
    const float* __restrict__ W3, u16* __restrict__ Wtb, u16* __restrict__ Wt3b){
  int b = blockIdx.x, t = threadIdx.x;
  if (b < 5860){
    int i = b*256 + t;
    if (i < RE){
      int r = i / EE;
      int s = src[i], d = dst[i];
      atomicAdd(&dout_cnt[r*NN + s], 1);
      int idx = r*NN + d;
      int pos = atomicAdd(&cursor[idx], 1);
      if (pos < idx*CAP + CAP) edge_src[pos] = s;   // overflow guard (P ~ 0)
    }
  } else if (b < 12110){
    int i = (b-5860)*256 + t;                       // 8 f32 -> 8 bf16
    if (i < NN*128/8){
      float4 v0 = ((const float4*)x)[i*2];
      float4 v1 = ((const float4*)x)[i*2+1];
      uint4 o;
      o.x = pk2(v0.x, v0.y); o.y = pk2(v0.z, v0.w);
      o.z = pk2(v1.x, v1.y); o.w = pk2(v1.z, v1.w);
      ((uint4*)xb)[i] = o;
    }
  } else if (b < 12686){
    int gid = (b-12110)*256 + t;                    // 3 layers x [3][128][128]
    if (gid < 3*3*16384){
      int l = gid / 49152; int rem = gid - l*49152; // rem = (r*128+k)*128+n
      int r = rem >> 14; int rem2 = rem & 16383;
      int k = rem2 >> 7; int n = rem2 & 127;
      const float* Wl = (l==0) ? W0 : (l==1) ? W1 : W2;
      Wtb[((size_t)(l*3+r))*16384 + (size_t)n*128 + k] = f2bf(Wl[rem]);
    }
  } else {
    int gid = (b-12686)*256 + t;                    // [3][128][32]
    if (gid < 3*4096){
      int r = gid >> 12; int rem = gid & 4095;
      int k = rem >> 5; int n = rem & 31;
      Wt3b[(size_t)(r*32+n)*128 + k] = f2bf(W3[gid]);
    }
  }
}

__global__ __launch_bounds__(256) void k_norms(const int* __restrict__ dout_cnt, float* __restrict__ dout_is){
  int i = blockIdx.x*256 + threadIdx.x;
  if (i < RN){
    int dc = dout_cnt[i] > 1 ? dout_cnt[i] : 1;
    dout_is[i] = rsqrtf((float)dc);
  }
}

// ---------------- aggregation (128 feats, bf16): quarter-wave gather ----------------
// lane = q*16+k: quarter q processes edges p = s0+q, s0+q+4, ...; lane covers feats 8k..8k+7
__global__ __launch_bounds__(256) void k_agg_bf(const u16* __restrict__ h, u16* __restrict__ AGG,
    const int* __restrict__ cursor, const int* __restrict__ edge_src,
    const float* __restrict__ dout_is){
  int w = (blockIdx.x*256 + threadIdx.x) >> 6;
  if (w >= RN) return;
  int l = threadIdx.x & 63;
  int q = l >> 4, k = l & 15;
  int r = w / NN;
  int n = w - r*NN;
  int s0 = w*CAP;
  int s1 = cursor[w];
  if (s1 > s0 + CAP) s1 = s0 + CAP;
  const float* __restrict__ dis = dout_is + r*NN;
  const uint4* __restrict__ h4 = (const uint4*)h;   // row = 16 uint4
  float a[8] = {0.f,0.f,0.f,0.f,0.f,0.f,0.f,0.f};
  for (int p = s0 + q; p < s1; p += 4){
    int s = edge_src[p];
    float wg = dis[s];
    uint4 v = h4[(size_t)s*16 + k];
    a[0] += wg*bf_lo(v.x); a[1] += wg*bf_hi(v.x);
    a[2] += wg*bf_lo(v.y); a[3] += wg*bf_hi(v.y);
    a[4] += wg*bf_lo(v.z); a[5] += wg*bf_hi(v.z);
    a[6] += wg*bf_lo(v.w); a[7] += wg*bf_hi(v.w);
  }
  #pragma unroll
  for (int i=0;i<8;i++){
    a[i] += __shfl_xor(a[i], 16);
    a[i] += __shfl_xor(a[i], 32);
  }
  if (q == 0){
    int cnt = s1 - s0;
    float di = rsqrtf((float)(cnt > 1 ? cnt : 1));
    uint4 o;
    o.x = pk2(a[0]*di, a[1]*di);
    o.y = pk2(a[2]*di, a[3]*di);
    o.z = pk2(a[4]*di, a[5]*di);
    o.w = pk2(a[6]*di, a[7]*di);
    ((uint4*)AGG)[(size_t)n*48 + r*16 + k] = o;   // AGG row = 48 uint4
  }
}

// ---------------- MFMA GEMM + per-relation ReLU ----------------
// 128x128 tile, 4 waves (2x2 of 64x64), 16x16x32 bf16 MFMA, XOR-swizzled LDS
__global__ __launch_bounds__(256) void k_mm_relu(const u16* __restrict__ A, const u16* __restrict__ Wt,
    const float* __restrict__ bias, u16* __restrict__ out){
  __shared__ __align__(16) u16 As[128*128];
  __shared__ __align__(16) u16 Bs[128*128];
  int t = threadIdx.x;
  int l = t & 63, w = t >> 6;
  int wr = w >> 1, wc = w & 1;
  int row0 = blockIdx.x * 128;
  int tr = t >> 4, tc = t & 15;
  int swz = tr & 7;

  f32x4 res[4][4];
  #pragma unroll
  for (int m=0;m<4;m++)
    #pragma unroll
    for (int n=0;n<4;n++) res[m][n] = (f32x4){0.f,0.f,0.f,0.f};

  for (int r=0; r<RR; r++){
    uint4 ra[8], rb[8];
    #pragma unroll
    for (int it=0; it<8; ++it){
      int grow = row0 + it*16 + tr;
      if (grow > NN-1) grow = NN-1;
      ra[it] = *(const uint4*)&A[(size_t)grow*KK + r*128 + tc*8];
      rb[it] = *(const uint4*)&Wt[(size_t)r*16384 + (size_t)(it*16 + tr)*128 + tc*8];
    }
    __syncthreads();
    #pragma unroll
    for (int it=0; it<8; ++it){
      int rho = it*16 + tr;
      int ch = (tc ^ swz) * 8;
      *(uint4*)&As[rho*128 + ch] = ra[it];
      *(uint4*)&Bs[rho*128 + ch] = rb[it];
    }
    __syncthreads();

    f32x4 acc[4][4];
    #pragma unroll
    for (int m=0;m<4;m++)
      #pragma unroll
      for (int n=0;n<4;n++) acc[m][n] = (f32x4){0.f,0.f,0.f,0.f};

    #pragma unroll
    for (int kk=0; kk<4; ++kk){
      bhalf8 af[4], bf[4];
      #pragma unroll
      for (int m=0;m<4;m++){
        int rho = wr*64 + m*16 + (l&15);
        int ch = (kk*4 + (l>>4)) ^ (l&7);
        af[m] = *(const bhalf8*)&As[rho*128 + ch*8];
      }
      #pragma unroll
      for (int n=0;n<4;n++){
        int rho = wc*64 + n*16 + (l&15);
        int ch = (kk*4 + (l>>4)) ^ (l&7);
        bf[n] = *(const bhalf8*)&Bs[rho*128 + ch*8];
      }
      #pragma unroll
      for (int m=0;m<4;m++)
        #pragma unroll
        for (int n=0;n<4;n++)
          acc[m][n] = __builtin_amdgcn_mfma_f32_16x16x32_bf16(af[m], bf[n], acc[m][n], 0, 0, 0);
    }

    #pragma unroll
    for (int n=0;n<4;n++){
      int col = wc*64 + n*16 + (l&15);
      float bb = bias[r*128 + col];
      #pragma unroll
      for (int m=0;m<4;m++)
        #pragma unroll
        for (int i=0;i<4;i++){
          float v = acc[m][n][i] + bb;
          res[m][n][i] += v > 0.f ? v : 0.f;
        }
    }
  }

  #pragma unroll
  for (int m=0;m<4;m++)
    #pragma unroll
    for (int i=0;i<4;i++){
      int grow = row0 + wr*64 + m*16 + (l>>4)*4 + i;
      if (grow < NN){
        #pragma unroll
        for (int n=0;n<4;n++)
          out[(size_t)grow*128 + wc*64 + n*16 + (l&15)] = f2bf(res[m][n][i]);
      }
    }
}

// ---------------- layer-3 transform GEMM: y[n][r*32+j] ----------------
__global__ __launch_bounds__(256) void k_mm_y(const u16* __restrict__ A, const u16* __restrict__ Wt3,
    u16* __restrict__ y){
  __shared__ __align__(16) u16 As[128*128];
  __shared__ __align__(16) u16 Bs[96*128];
  int t = threadIdx.x;
  int l = t & 63, w = t >> 6;
  int wr = w & 1, wc = w >> 1;
  int row0 = blockIdx.x * 128;
  int tr = t >> 4, tc = t & 15;
  int swz = tr & 7;

  uint4 ra[8], rb[6];
  #pragma unroll
  for (int it=0; it<8; ++it){
    int grow = row0 + it*16 + tr;
    if (grow > NN-1) grow = NN-1;
    ra[it] = *(const uint4*)&A[(size_t)grow*128 + tc*8];
  }
  #pragma unroll
  for (int it=0; it<6; ++it)
    rb[it] = *(const uint4*)&Wt3[(size_t)(it*16 + tr)*128 + tc*8];
  #pragma unroll
  for (int it=0; it<8; ++it)
    *(uint4*)&As[(it*16+tr)*128 + ((tc ^ swz)*8)] = ra[it];
  #pragma unroll
  for (int it=0; it<6; ++it)
    *(uint4*)&Bs[(it*16+tr)*128 + ((tc ^ swz)*8)] = rb[it];
  __syncthreads();

  f32x4 acc[4][3];
  #pragma unroll
  for (int m=0;m<4;m++)
    #pragma unroll
    for (int n=0;n<3;n++) acc[m][n] = (f32x4){0.f,0.f,0.f,0.f};

  #pragma unroll
  for (int kk=0; kk<4; ++kk){
    bhalf8 af[4], bf[3];
    #pragma unroll
    for (int m=0;m<4;m++){
      int rho = wr*64 + m*16 + (l&15);
      int ch = (kk*4 + (l>>4)) ^ (l&7);
      af[m] = *(const bhalf8*)&As[rho*128 + ch*8];
    }
    #pragma unroll
    for (int n=0;n<3;n++){
      int rho = wc*48 + n*16 + (l&15);
      int ch = (kk*4 + (l>>4)) ^ (l&7);
      bf[n] = *(const bhalf8*)&Bs[rho*128 + ch*8];
    }
    #pragma unroll
    for (int m=0;m<4;m++)
      #pragma unroll
      for (int n=0;n<3;n++)
        acc[m][n] = __builtin_amdgcn_mfma_f32_16x16x32_bf16(af[m], bf[n], acc[m][n], 0, 0, 0);
  }

  #pragma unroll
  for (int m=0;m<4;m++)
    #pragma unroll
    for (int i=0;i<4;i++){
      int grow = row0 + wr*64 + m*16 + (l>>4)*4 + i;
      if (grow < NN){
        #pragma unroll
        for (int n=0;n<3;n++)
          y[(size_t)grow*96 + wc*48 + n*16 + (l&15)] = f2bf(acc[m][n][i]);
      }
    }
}

// ---------------- final aggregation over 32 feats: 8 lane-groups x 4 feats ----------------
__global__ __launch_bounds__(256) void k_agg_out(const u16* __restrict__ y, float* __restrict__ out,
    const int* __restrict__ cursor, const int* __restrict__ edge_src,
    const float* __restrict__ dout_is, const float* __restrict__ b3){
  int n = (blockIdx.x*256 + threadIdx.x) >> 6;
  if (n >= NN) return;
  int l = threadIdx.x & 63;
  int g = l >> 3, k = l & 7;
  float res[4];
  #pragma unroll
  for (int i=0;i<4;i++) res[i] = b3[4*k+i] + b3[32+4*k+i] + b3[64+4*k+i];
  const uint2* __restrict__ y2 = (const uint2*)y;   // y row = 24 uint2
  for (int r=0; r<RR; r++){
    int w = r*NN + n;
    int s0 = w*CAP;
    int s1 = cursor[w];
    if (s1 > s0 + CAP) s1 = s0 + CAP;
    const float* __restrict__ dis = dout_is + r*NN;
    float a[4] = {0.f,0.f,0.f,0.f};
    for (int p = s0 + g; p < s1; p += 8){
      int s = edge_src[p];
      float wg = dis[s];
      uint2 v = y2[(size_t)s*24 + r*8 + k];
      a[0] += wg*bf_lo(v.x); a[1] += wg*bf_hi(v.x);
      a[2] += wg*bf_lo(v.y); a[3] += wg*bf_hi(v.y);
    }
    #pragma unroll
    for (int i=0;i<4;i++){
      a[i] += __shfl_xor(a[i], 8);
      a[i] += __shfl_xor(a[i], 16);
      a[i] += __shfl_xor(a[i], 32);
    }
    int cnt = s1 - s0;
    float di = rsqrtf((float)(cnt>1?cnt:1));
    #pragma unroll
    for (int i=0;i<4;i++) res[i] += di*a[i];
  }
  if (g == 0)
    ((float4*)out)[(size_t)n*8 + k] = make_float4(res[0],res[1],res[2],res[3]);
}

// ---------------- launch ----------------

extern "C" void kernel_launch(void* const* d_in, const int* in_sizes, int n_in,
                              void* d_out, int out_size, void* d_ws, size_t ws_size,
                              hipStream_t stream){
  const float* x   = (const float*)d_in[0];
  const int*   src = (const int*)d_in[1];
  const int*   dst = (const int*)d_in[2];
  const float* W0  = (const float*)d_in[3]; const float* b0 = (const float*)d_in[4];
  const float* W1  = (const float*)d_in[5]; const float* b1 = (const float*)d_in[6];
  const float* W2  = (const float*)d_in[7]; const float* b2 = (const float*)d_in[8];
  const float* W3  = (const float*)d_in[9]; const float* b3 = (const float*)d_in[10];
  float* out = (float*)d_out;

  // workspace layout (~133 MB; known-good ws >= ~141 MB)
  char* p = (char*)d_ws;
  auto alloc = [&](size_t bytes)->char*{
    char* q = p; p += (bytes + 255) & ~(size_t)255; return q;
  };
  int*   cursor   = (int*)  alloc(RN*4);
  int*   dout_cnt = (int*)  alloc(RN*4);
  float* dout_is  = (float*)alloc(RN*4);
  u16*   Wtb      = (u16*)  alloc((size_t)3*3*16384*2);
  u16*   Wt3b     = (u16*)  alloc((size_t)3*32*128*2);
  u16*   AGG      = (u16*)  alloc((size_t)NN*KK*2);    // 76.8 MB; low 19.2 MB reused as y
  u16*   bufA     = (u16*)  alloc((size_t)NN*128*2);   // 25.6 MB
  u16*   bufB     = (u16*)  alloc((size_t)NN*128*2);   // 25.6 MB (xb first)
  int*   edge_src = (int*)  alloc((size_t)RN*CAP*4);   // 38.4 MB padded CSR
  u16*   y        = AGG;                               // overlay (AGG dead by layer 3)

  k_init <<<cdiv_h(RN,256),256,0,stream>>>(cursor, dout_cnt);
  k_pre1f<<<12734,256,0,stream>>>(src, dst, cursor, dout_cnt, edge_src,
                                  x, bufB, W0,W1,W2,W3, Wtb, Wt3b);
  k_norms<<<cdiv_h(RN,256),256,0,stream>>>(dout_cnt, dout_is);

  int agg_blocks = cdiv_h(RN,4);
  int mm_blocks  = cdiv_h(NN,128);

  // layer 0: xb(bufB) -> AGG -> h0(bufA)
  k_agg_bf<<<agg_blocks,256,0,stream>>>(bufB, AGG, cursor, edge_src, dout_is);
  k_mm_relu<<<mm_blocks,256,0,stream>>>(AGG, Wtb, b0, bufA);
  // layer 1: h0(bufA) -> AGG -> h1(bufB)
  k_agg_bf<<<agg_blocks,256,0,stream>>>(bufA, AGG, cursor, edge_src, dout_is);
  k_mm_relu<<<mm_blocks,256,0,stream>>>(AGG, Wtb + 3*16384, b1, bufB);
  // layer 2: h1(bufB) -> AGG -> h2(bufA)
  k_agg_bf<<<agg_blocks,256,0,stream>>>(bufB, AGG, cursor, edge_src, dout_is);
  k_mm_relu<<<mm_blocks,256,0,stream>>>(AGG, Wtb + 6*16384, b2, bufA);
  // layer 3: transform-first then 32-feat aggregation
  k_mm_y<<<mm_blocks,256,0,stream>>>(bufA, Wt3b, y);
  k_agg_out<<<cdiv_h(NN,4),256,0,stream>>>(y, out, cursor, edge_src, dout_is, b3);
}

// Round 9
// 655.261 us; speedup vs baseline: 1.2343x; 1.1847x over previous
//
#include <hip/hip_runtime.h>
#include <cstdint>
#include <cstddef>

#define NN 100000
#define RR 3
#define EE 500000
#define RN 300000   // RR*NN
#define RE 1500000  // RR*EE
#define KK 384      // RR*128
#define CAP 32      // padded-CSR slots per (rel,node)

typedef unsigned short u16;
typedef unsigned int   u32;
typedef __attribute__((ext_vector_type(8))) short bhalf8;
typedef __attribute__((ext_vector_type(4))) float f32x4;
typedef __attribute__((ext_vector_type(4))) unsigned int u32x4;
typedef __attribute__((ext_vector_type(2))) unsigned int u32x2;

static inline int cdiv_h(int a, int b){ return (a+b-1)/b; }

__device__ __forceinline__ float bf_lo(u32 v){ union{u32 u; float f;} c; c.u = v<<16; return c.f; }
__device__ __forceinline__ float bf_hi(u32 v){ union{u32 u; float f;} c; c.u = v & 0xffff0000u; return c.f; }
__device__ __forceinline__ u16 f2bf(float f){
  union{float f; u32 u;} c; c.f = f;
  u32 r = (c.u + 0x7FFFu + ((c.u >> 16) & 1u)) >> 16;  // RNE
  return (u16)r;
}
__device__ __forceinline__ u32 pk2(float a, float b){ return (u32)f2bf(a) | ((u32)f2bf(b)<<16); }
__device__ __forceinline__ float invdeg(int c){ return rsqrtf((float)(c > 1 ? c : 1)); }

// ---------------- init: cursors + dout counters ----------------
__global__ __launch_bounds__(256) void k_init(int* __restrict__ cursor, int* __restrict__ dout_cnt){
  int i = blockIdx.x*256 + threadIdx.x;
  if (i < RN){ cursor[i] = i*CAP; dout_cnt[i] = 0; }
}

// ---------------- fused: CSR fill+dout hist (atomic) || x->bf16 || W transposes ----------------
// blocks [0,5860) edges  [5860,12110) cvt_x  [12110,12686) Wt012  [12686,12734) Wt3
__global__ __launch_bounds__(256) void k_pre1f(const int* __restrict__ src, const int* __restrict__ dst,
    int* __restrict__ cursor, int* __restrict__ dout_cnt, int* __restrict__ edge_src,
    const float* __restrict__ x, u16* __restrict__ xb,
    const float* __restrict__ W0, const float* __restrict__ W1, const float* __restrict__ W2,
    const float* __restrict__ W3, u16* __restrict__ Wtb, u16* __restrict__ Wt3b){
  int b = blockIdx.x, t = threadIdx.x;
  if (b < 5860){
    int i = b*256 + t;
    if (i < RE){
      int r = i / EE;
      int s = src[i], d = dst[i];
      atomicAdd(&dout_cnt[r*NN + s], 1);
      int idx = r*NN + d;
      int pos = atomicAdd(&cursor[idx], 1);
      if (pos < idx*CAP + CAP) edge_src[pos] = s;   // overflow guard (P ~ 0)
    }
  } else if (b < 12110){
    int i = (b-5860)*256 + t;                       // 8 f32 -> 8 bf16
    if (i < NN*128/8){
      float4 v0 = ((const float4*)x)[i*2];
      float4 v1 = ((const float4*)x)[i*2+1];
      u32x4 o;
      o.x = pk2(v0.x, v0.y); o.y = pk2(v0.z, v0.w);
      o.z = pk2(v1.x, v1.y); o.w = pk2(v1.z, v1.w);
      __builtin_nontemporal_store(o, &((u32x4*)xb)[i]);
    }
  } else if (b < 12686){
    int gid = (b-12110)*256 + t;                    // 3 layers x [3][128][128]
    if (gid < 3*3*16384){
      int l = gid / 49152; int rem = gid - l*49152; // rem = (r*128+k)*128+n
      int r = rem >> 14; int rem2 = rem & 16383;
      int k = rem2 >> 7; int n = rem2 & 127;
      const float* Wl = (l==0) ? W0 : (l==1) ? W1 : W2;
      __builtin_nontemporal_store(f2bf(Wl[rem]),
          &Wtb[((size_t)(l*3+r))*16384 + (size_t)n*128 + k]);
    }
  } else {
    int gid = (b-12686)*256 + t;                    // [3][128][32]
    if (gid < 3*4096){
      int r = gid >> 12; int rem = gid & 4095;
      int k = rem >> 5; int n = rem & 31;
      __builtin_nontemporal_store(f2bf(W3[gid]),
          &Wt3b[(size_t)(r*32+n)*128 + k]);
    }
  }
}

// ---------------- aggregation (128 feats, bf16): quarter-wave gather ----------------
// lane = q*16+k: quarter q processes edges p = s0+q, s0+q+4, ...; lane covers feats 8k..8k+7
__global__ __launch_bounds__(256) void k_agg_bf(const u16* __restrict__ h, u16* __restrict__ AGG,
    const int* __restrict__ cursor, const int* __restrict__ edge_src,
    const int* __restrict__ dout_cnt){
  int w = (blockIdx.x*256 + threadIdx.x) >> 6;
  if (w >= RN) return;
  int l = threadIdx.x & 63;
  int q = l >> 4, k = l & 15;
  int r = w / NN;
  int n = w - r*NN;
  int s0 = w*CAP;
  int s1 = cursor[w];
  if (s1 > s0 + CAP) s1 = s0 + CAP;
  const int* __restrict__ dct = dout_cnt + r*NN;
  const u32x4* __restrict__ h4 = (const u32x4*)h;   // row = 16 u32x4
  float a[8] = {0.f,0.f,0.f,0.f,0.f,0.f,0.f,0.f};
  for (int p = s0 + q; p < s1; p += 4){
    int s = edge_src[p];
    float wg = invdeg(dct[s]);
    u32x4 v = h4[(size_t)s*16 + k];
    a[0] += wg*bf_lo(v.x); a[1] += wg*bf_hi(v.x);
    a[2] += wg*bf_lo(v.y); a[3] += wg*bf_hi(v.y);
    a[4] += wg*bf_lo(v.z); a[5] += wg*bf_hi(v.z);
    a[6] += wg*bf_lo(v.w); a[7] += wg*bf_hi(v.w);
  }
  #pragma unroll
  for (int i=0;i<8;i++){
    a[i] += __shfl_xor(a[i], 16);
    a[i] += __shfl_xor(a[i], 32);
  }
  if (q == 0){
    float di = invdeg(s1 - s0);
    u32x4 o;
    o.x = pk2(a[0]*di, a[1]*di);
    o.y = pk2(a[2]*di, a[3]*di);
    o.z = pk2(a[4]*di, a[5]*di);
    o.w = pk2(a[6]*di, a[7]*di);
    __builtin_nontemporal_store(o, &((u32x4*)AGG)[(size_t)n*48 + r*16 + k]);  // AGG row = 48 u32x4
  }
}

// ---------------- MFMA GEMM + per-relation ReLU (A-prefetch pipelined) ----------------
// 128x128 tile, 4 waves (2x2 of 64x64), 16x16x32 bf16 MFMA, XOR-swizzled LDS
__global__ __launch_bounds__(256) void k_mm_relu(const u16* __restrict__ A, const u16* __restrict__ Wt,
    const float* __restrict__ bias, u16* __restrict__ out){
  __shared__ __align__(16) u16 As[128*128];
  __shared__ __align__(16) u16 Bs[128*128];
  int t = threadIdx.x;
  int l = t & 63, w = t >> 6;
  int wr = w >> 1, wc = w & 1;
  int row0 = blockIdx.x * 128;
  int tr = t >> 4, tc = t & 15;
  int swz = tr & 7;

  // per-thread A source rows (clamped)
  int grow[8];
  #pragma unroll
  for (int it=0; it<8; ++it){
    int gr = row0 + it*16 + tr;
    grow[it] = gr > NN-1 ? NN-1 : gr;
  }

  f32x4 res[4][4];
  #pragma unroll
  for (int m=0;m<4;m++)
    #pragma unroll
    for (int n=0;n<4;n++) res[m][n] = (f32x4){0.f,0.f,0.f,0.f};

  // stage r=0
  u32x4 ra[8];
  #pragma unroll
  for (int it=0; it<8; ++it){
    ra[it] = __builtin_nontemporal_load((const u32x4*)&A[(size_t)grow[it]*KK + tc*8]);
    u32x4 rb = *(const u32x4*)&Wt[(size_t)(it*16 + tr)*128 + tc*8];
    *(u32x4*)&Bs[(it*16+tr)*128 + ((tc ^ swz)*8)] = rb;
  }
  #pragma unroll
  for (int it=0; it<8; ++it)
    *(u32x4*)&As[(it*16+tr)*128 + ((tc ^ swz)*8)] = ra[it];
  __syncthreads();

  for (int r=0; r<RR; r++){
    // prefetch next relation's A-tile while MFMA runs
    if (r+1 < RR){
      #pragma unroll
      for (int it=0; it<8; ++it)
        ra[it] = __builtin_nontemporal_load((const u32x4*)&A[(size_t)grow[it]*KK + (r+1)*128 + tc*8]);
    }

    f32x4 acc[4][4];
    #pragma unroll
    for (int m=0;m<4;m++)
      #pragma unroll
      for (int n=0;n<4;n++) acc[m][n] = (f32x4){0.f,0.f,0.f,0.f};

    #pragma unroll
    for (int kk=0; kk<4; ++kk){
      bhalf8 af[4], bf[4];
      #pragma unroll
      for (int m=0;m<4;m++){
        int rho = wr*64 + m*16 + (l&15);
        int ch = (kk*4 + (l>>4)) ^ (l&7);
        af[m] = *(const bhalf8*)&As[rho*128 + ch*8];
      }
      #pragma unroll
      for (int n=0;n<4;n++){
        int rho = wc*64 + n*16 + (l&15);
        int ch = (kk*4 + (l>>4)) ^ (l&7);
        bf[n] = *(const bhalf8*)&Bs[rho*128 + ch*8];
      }
      #pragma unroll
      for (int m=0;m<4;m++)
        #pragma unroll
        for (int n=0;n<4;n++)
          acc[m][n] = __builtin_amdgcn_mfma_f32_16x16x32_bf16(af[m], bf[n], acc[m][n], 0, 0, 0);
    }

    #pragma unroll
    for (int n=0;n<4;n++){
      int col = wc*64 + n*16 + (l&15);
      float bb = bias[r*128 + col];
      #pragma unroll
      for (int m=0;m<4;m++)
        #pragma unroll
        for (int i=0;i<4;i++){
          float v = acc[m][n][i] + bb;
          res[m][n][i] += v > 0.f ? v : 0.f;
        }
    }

    if (r+1 < RR){
      __syncthreads();   // all waves done reading LDS
      #pragma unroll
      for (int it=0; it<8; ++it){
        u32x4 rb = *(const u32x4*)&Wt[(size_t)(r+1)*16384 + (size_t)(it*16 + tr)*128 + tc*8];
        *(u32x4*)&As[(it*16+tr)*128 + ((tc ^ swz)*8)] = ra[it];
        *(u32x4*)&Bs[(it*16+tr)*128 + ((tc ^ swz)*8)] = rb;
      }
      __syncthreads();
    }
  }

  #pragma unroll
  for (int m=0;m<4;m++)
    #pragma unroll
    for (int i=0;i<4;i++){
      int gr = row0 + wr*64 + m*16 + (l>>4)*4 + i;
      if (gr < NN){
        #pragma unroll
        for (int n=0;n<4;n++)
          out[(size_t)gr*128 + wc*64 + n*16 + (l&15)] = f2bf(res[m][n][i]);
      }
    }
}

// ---------------- layer-3 transform GEMM: y[r][n][32] ----------------
__global__ __launch_bounds__(256) void k_mm_y(const u16* __restrict__ A, const u16* __restrict__ Wt3,
    u16* __restrict__ y){
  __shared__ __align__(16) u16 As[128*128];
  __shared__ __align__(16) u16 Bs[96*128];
  int t = threadIdx.x;
  int l = t & 63, w = t >> 6;
  int wr = w & 1, wc = w >> 1;
  int row0 = blockIdx.x * 128;
  int tr = t >> 4, tc = t & 15;
  int swz = tr & 7;

  u32x4 ra[8], rb[6];
  #pragma unroll
  for (int it=0; it<8; ++it){
    int grow = row0 + it*16 + tr;
    if (grow > NN-1) grow = NN-1;
    ra[it] = __builtin_nontemporal_load((const u32x4*)&A[(size_t)grow*128 + tc*8]);
  }
  #pragma unroll
  for (int it=0; it<6; ++it)
    rb[it] = *(const u32x4*)&Wt3[(size_t)(it*16 + tr)*128 + tc*8];
  #pragma unroll
  for (int it=0; it<8; ++it)
    *(u32x4*)&As[(it*16+tr)*128 + ((tc ^ swz)*8)] = ra[it];
  #pragma unroll
  for (int it=0; it<6; ++it)
    *(u32x4*)&Bs[(it*16+tr)*128 + ((tc ^ swz)*8)] = rb[it];
  __syncthreads();

  f32x4 acc[4][3];
  #pragma unroll
  for (int m=0;m<4;m++)
    #pragma unroll
    for (int n=0;n<3;n++) acc[m][n] = (f32x4){0.f,0.f,0.f,0.f};

  #pragma unroll
  for (int kk=0; kk<4; ++kk){
    bhalf8 af[4], bf[3];
    #pragma unroll
    for (int m=0;m<4;m++){
      int rho = wr*64 + m*16 + (l&15);
      int ch = (kk*4 + (l>>4)) ^ (l&7);
      af[m] = *(const bhalf8*)&As[rho*128 + ch*8];
    }
    #pragma unroll
    for (int n=0;n<3;n++){
      int rho = wc*48 + n*16 + (l&15);
      int ch = (kk*4 + (l>>4)) ^ (l&7);
      bf[n] = *(const bhalf8*)&Bs[rho*128 + ch*8];
    }
    #pragma unroll
    for (int m=0;m<4;m++)
      #pragma unroll
      for (int n=0;n<3;n++)
        acc[m][n] = __builtin_amdgcn_mfma_f32_16x16x32_bf16(af[m], bf[n], acc[m][n], 0, 0, 0);
  }

  // store: col c = wc*48 + n*16 + (l&15) -> rel = c>>5, j = c&31; y[(rel*NN + row)*32 + j]
  #pragma unroll
  for (int m=0;m<4;m++)
    #pragma unroll
    for (int i=0;i<4;i++){
      int gr = row0 + wr*64 + m*16 + (l>>4)*4 + i;
      if (gr < NN){
        #pragma unroll
        for (int n=0;n<3;n++){
          int c = wc*48 + n*16 + (l&15);
          y[((size_t)(c>>5)*NN + gr)*32 + (c&31)] = f2bf(acc[m][n][i]);
        }
      }
    }
}

// ---------------- final aggregation over 32 feats: 8 lane-groups x 4 feats ----------------
__global__ __launch_bounds__(256) void k_agg_out(const u16* __restrict__ y, float* __restrict__ out,
    const int* __restrict__ cursor, const int* __restrict__ edge_src,
    const int* __restrict__ dout_cnt, const float* __restrict__ b3){
  int n = (blockIdx.x*256 + threadIdx.x) >> 6;
  if (n >= NN) return;
  int l = threadIdx.x & 63;
  int g = l >> 3, k = l & 7;
  float res[4];
  #pragma unroll
  for (int i=0;i<4;i++) res[i] = b3[4*k+i] + b3[32+4*k+i] + b3[64+4*k+i];
  const u32x2* __restrict__ y2 = (const u32x2*)y;   // per-rel row = 8 u32x2
  for (int r=0; r<RR; r++){
    int w = r*NN + n;
    int s0 = w*CAP;
    int s1 = cursor[w];
    if (s1 > s0 + CAP) s1 = s0 + CAP;
    const int* __restrict__ dct = dout_cnt + r*NN;
    float a[4] = {0.f,0.f,0.f,0.f};
    for (int p = s0 + g; p < s1; p += 8){
      int s = edge_src[p];
      float wg = invdeg(dct[s]);
      u32x2 v = y2[((size_t)r*NN + s)*8 + k];
      a[0] += wg*bf_lo(v.x); a[1] += wg*bf_hi(v.x);
      a[2] += wg*bf_lo(v.y); a[3] += wg*bf_hi(v.y);
    }
    #pragma unroll
    for (int i=0;i<4;i++){
      a[i] += __shfl_xor(a[i], 8);
      a[i] += __shfl_xor(a[i], 16);
      a[i] += __shfl_xor(a[i], 32);
    }
    float di = invdeg(s1 - s0);
    #pragma unroll
    for (int i=0;i<4;i++) res[i] += di*a[i];
  }
  if (g == 0)
    ((float4*)out)[(size_t)n*8 + k] = make_float4(res[0],res[1],res[2],res[3]);
}

// ---------------- launch ----------------

extern "C" void kernel_launch(void* const* d_in, const int* in_sizes, int n_in,
                              void* d_out, int out_size, void* d_ws, size_t ws_size,
                              hipStream_t stream){
  const float* x   = (const float*)d_in[0];
  const int*   src = (const int*)d_in[1];
  const int*   dst = (const int*)d_in[2];
  const float* W0  = (const float*)d_in[3]; const float* b0 = (const float*)d_in[4];
  const float* W1  = (const float*)d_in[5]; const float* b1 = (const float*)d_in[6];
  const float* W2  = (const float*)d_in[7]; const float* b2 = (const float*)d_in[8];
  const float* W3  = (const float*)d_in[9]; const float* b3 = (const float*)d_in[10];
  float* out = (float*)d_out;

  // workspace layout (~132 MB; known-good ws >= ~141 MB)
  char* p = (char*)d_ws;
  auto alloc = [&](size_t bytes)->char*{
    char* q = p; p += (bytes + 255) & ~(size_t)255; return q;
  };
  int*   cursor   = (int*)  alloc(RN*4);
  int*   dout_cnt = (int*)  alloc(RN*4);
  u16*   Wtb      = (u16*)  alloc((size_t)3*3*16384*2);
  u16*   Wt3b     = (u16*)  alloc((size_t)3*32*128*2);
  u16*   AGG      = (u16*)  alloc((size_t)NN*KK*2);    // 76.8 MB; low 19.2 MB reused as y
  u16*   bufA     = (u16*)  alloc((size_t)NN*128*2);   // 25.6 MB
  u16*   bufB     = (u16*)  alloc((size_t)NN*128*2);   // 25.6 MB (xb first)
  int*   edge_src = (int*)  alloc((size_t)RN*CAP*4);   // 38.4 MB padded CSR
  u16*   y        = AGG;                               // overlay (AGG dead by layer 3)

  k_init <<<cdiv_h(RN,256),256,0,stream>>>(cursor, dout_cnt);
  k_pre1f<<<12734,256,0,stream>>>(src, dst, cursor, dout_cnt, edge_src,
                                  x, bufB, W0,W1,W2,W3, Wtb, Wt3b);

  int agg_blocks = cdiv_h(RN,4);
  int mm_blocks  = cdiv_h(NN,128);

  // layer 0: xb(bufB) -> AGG -> h0(bufA)
  k_agg_bf<<<agg_blocks,256,0,stream>>>(bufB, AGG, cursor, edge_src, dout_cnt);
  k_mm_relu<<<mm_blocks,256,0,stream>>>(AGG, Wtb, b0, bufA);
  // layer 1: h0(bufA) -> AGG -> h1(bufB)
  k_agg_bf<<<agg_blocks,256,0,stream>>>(bufA, AGG, cursor, edge_src, dout_cnt);
  k_mm_relu<<<mm_blocks,256,0,stream>>>(AGG, Wtb + 3*16384, b1, bufB);
  // layer 2: h1(bufB) -> AGG -> h2(bufA)
  k_agg_bf<<<agg_blocks,256,0,stream>>>(bufB, AGG, cursor, edge_src, dout_cnt);
  k_mm_relu<<<mm_blocks,256,0,stream>>>(AGG, Wtb + 6*16384, b2, bufA);
  // layer 3: transform-first then 32-feat aggregation
  k_mm_y<<<mm_blocks,256,0,stream>>>(bufA, Wt3b, y);
  k_agg_out<<<cdiv_h(NN,4),256,0,stream>>>(y, out, cursor, edge_src, dout_cnt, b3);
}